// Round 8
// baseline (352.689 us; speedup 1.0000x reference)
//
#include <hip/hip_runtime.h>

#define D 128

typedef __attribute__((ext_vector_type(8))) short bf16x8;   // 8 bf16 = 4 VGPR
typedef __attribute__((ext_vector_type(4))) float f32x4;    // MFMA C/D
typedef __attribute__((ext_vector_type(4))) float fx4;
typedef __attribute__((ext_vector_type(4))) short sx4;
typedef __attribute__((ext_vector_type(8))) short sx8;

static __device__ __forceinline__ short f2bf(float f) {  // RNE bf16 bits
    union { float f; unsigned u; } v; v.f = f;
    const unsigned r = v.u + 0x7FFFu + ((v.u >> 16) & 1u);
    return (short)(r >> 16);
}
static __device__ __forceinline__ float bf2f(short s) {
    union { unsigned u; float f; } v;
    v.u = ((unsigned)(unsigned short)s) << 16;
    return v.f;
}

// ===== k_prep: nfeat->bf16 convert, W transpose->bf16, zero cnt/stats =====
__global__ __launch_bounds__(256) void k_prep(
    const float* __restrict__ nfeat, short* __restrict__ nfb,
    const float* __restrict__ W1, const float* __restrict__ W2,
    const float* __restrict__ We, short* __restrict__ Wt1,
    short* __restrict__ Wt2, short* __restrict__ Wte,
    int* __restrict__ cnt, float* __restrict__ stats,
    int N, int nbConv, int nbW)
{
    const int b = blockIdx.x, t = threadIdx.x;
    if (b < nbConv) {
        const int i = b * 256 + t;
        if (i < (N * D) / 4) {
            const float4 v = ((const float4*)nfeat)[i];
            short4 s;
            s.x = f2bf(v.x); s.y = f2bf(v.y); s.z = f2bf(v.z); s.w = f2bf(v.w);
            ((short4*)nfb)[i] = s;
        }
    } else if (b < nbConv + nbW) {
        const int i = (b - nbConv) * 256 + t;   // 0 .. 49151
        const int m = i >> 14;
        const int idx = i & 16383;
        const int k = idx >> 7, n = idx & 127;
        const float* W = (m == 0) ? W1 : (m == 1) ? W2 : We;
        short* Wt = (m == 0) ? Wt1 : (m == 1) ? Wt2 : Wte;
        Wt[n * 128 + k] = f2bf(W[k * 128 + n]);
    } else {
        const int i = (b - nbConv - nbW) * 256 + t;
        if (i * 4 < N) ((int4*)cnt)[i] = make_int4(0, 0, 0, 0);
        if (b == nbConv + nbW && t < 256) stats[t] = 0.f;
    }
}

// ================= CSR build =================
__global__ void k_hist(const int* __restrict__ dst, int* __restrict__ cnt, int E) {
    const int base = (blockIdx.x * 256 + threadIdx.x) * 4;
    if (base + 3 < E) {
        const int4 d4 = *(const int4*)(dst + base);
        atomicAdd(&cnt[d4.x], 1);
        atomicAdd(&cnt[d4.y], 1);
        atomicAdd(&cnt[d4.z], 1);
        atomicAdd(&cnt[d4.w], 1);
    } else {
        for (int e = base; e < E; ++e) atomicAdd(&cnt[dst[e]], 1);
    }
}

// ===== single-block multi-tile exclusive scan =====
__global__ __launch_bounds__(1024) void k_scan(
    const int* __restrict__ cnt, int* __restrict__ row_ptr,
    int* __restrict__ cursor, float* __restrict__ degf, int N)
{
    __shared__ int ws[17];
    const int t = threadIdx.x, lane = t & 63, wid = t >> 6;
    int carry = 0;
    const int ntiles = (N + 4095) / 4096;
    for (int tile = 0; tile < ntiles; ++tile) {
        const int base = tile * 4096 + t * 4;
        int4 v = make_int4(0, 0, 0, 0);
        if (base + 3 < N) v = *(const int4*)(cnt + base);
        else {
            if (base     < N) v.x = cnt[base];
            if (base + 1 < N) v.y = cnt[base + 1];
            if (base + 2 < N) v.z = cnt[base + 2];
            if (base + 3 < N) v.w = cnt[base + 3];
        }
        const int s = v.x + v.y + v.z + v.w;
        int incl = s;
        #pragma unroll
        for (int off = 1; off < 64; off <<= 1) {
            const int u = __shfl_up(incl, off);
            if (lane >= off) incl += u;
        }
        if (lane == 63) ws[wid] = incl;
        __syncthreads();
        if (t < 16) {
            const int wv = ws[t];
            int wincl = wv;
            #pragma unroll
            for (int off = 1; off < 16; off <<= 1) {
                const int u = __shfl_up(wincl, off);
                if (t >= off) wincl += u;
            }
            ws[t] = wincl - wv;
            if (t == 15) ws[16] = wincl;
        }
        __syncthreads();
        const int ex = carry + ws[wid] + (incl - s);
        if (base + 3 < N) {
            const int4 rp = make_int4(ex, ex + v.x, ex + v.x + v.y,
                                      ex + v.x + v.y + v.z);
            *(int4*)(row_ptr + base) = rp;
            *(int4*)(cursor + base)  = rp;
            *(float4*)(degf + base)  =
                make_float4((float)v.x, (float)v.y, (float)v.z, (float)v.w);
        } else {
            int run = ex;
            if (base < N)     { row_ptr[base]   = run; cursor[base]   = run; degf[base]   = (float)v.x; run += v.x; }
            if (base + 1 < N) { row_ptr[base+1] = run; cursor[base+1] = run; degf[base+1] = (float)v.y; run += v.y; }
            if (base + 2 < N) { row_ptr[base+2] = run; cursor[base+2] = run; degf[base+2] = (float)v.z; run += v.z; }
            if (base + 3 < N) { row_ptr[base+3] = run; cursor[base+3] = run; degf[base+3] = (float)v.w; }
        }
        carry += ws[16];
        __syncthreads();
    }
    if (t == 0) row_ptr[N] = carry;
}

// ===== scatter: pos[e] = CSR slot (seq store); esrcc[slot] = src (random 4B)
__global__ void k_scatter(const int* __restrict__ src, const int* __restrict__ dst,
                          int* __restrict__ cursor,
                          int* __restrict__ pos, int* __restrict__ esrcc, int E) {
    const int base = (blockIdx.x * 256 + threadIdx.x) * 4;
    if (base + 3 < E) {
        const int4 d4 = *(const int4*)(dst + base);
        const int4 s4 = *(const int4*)(src + base);
        int4 p4;
        p4.x = atomicAdd(&cursor[d4.x], 1); esrcc[p4.x] = s4.x;
        p4.y = atomicAdd(&cursor[d4.y], 1); esrcc[p4.y] = s4.y;
        p4.z = atomicAdd(&cursor[d4.z], 1); esrcc[p4.z] = s4.z;
        p4.w = atomicAdd(&cursor[d4.w], 1); esrcc[p4.w] = s4.w;
        *(int4*)(pos + base) = p4;
    } else {
        for (int e = base; e < E; ++e) {
            const int p = atomicAdd(&cursor[dst[e]], 1);
            esrcc[p] = src[e];
            pos[e] = p;
        }
    }
}

// ===== perm: edge-order pass. Sequential efeat read (full stream BW),
// bf16 convert, write row to CSR slot (random 256B burst, fire-and-forget).
__global__ __launch_bounds__(256) void k_perm(
    const float* __restrict__ efeat, const int* __restrict__ pos,
    short* __restrict__ ecsr, int E)
{
    const int t = threadIdx.x;
    const int e = blockIdx.x * 16 + (t >> 4);
    const int l = t & 15;            // 16 lanes/edge: 16x32B read, 16x16B write
    if (e >= E) return;
    const float* ep = efeat + (size_t)e * D + l * 8;
    const fx4 v0 = __builtin_nontemporal_load((const fx4*)ep);
    const fx4 v1 = __builtin_nontemporal_load((const fx4*)ep + 1);
    sx8 o;
    o[0] = f2bf(v0[0]); o[1] = f2bf(v0[1]); o[2] = f2bf(v0[2]); o[3] = f2bf(v0[3]);
    o[4] = f2bf(v1[0]); o[5] = f2bf(v1[1]); o[6] = f2bf(v1[2]); o[7] = f2bf(v1[3]);
    const int p = pos[e];
    *(sx8*)(ecsr + (size_t)p * D + l * 8) = o;
}

// ===== sum: half-wave per node. ecsr read SEQUENTIALLY (2 rows/iter, 512B
// contiguous per half-wave), nfb random (L2/L3-served).
__global__ __launch_bounds__(256) void k_sum(
    const short* __restrict__ nfb, const short* __restrict__ ecsr,
    const int* __restrict__ row_ptr, const int* __restrict__ esrcc,
    short* __restrict__ xbuf, short* __restrict__ agg_e, int N)
{
    const int t = threadIdx.x;
    const int L = t & 31;        // lane in half-wave
    const int hl = L & 15;       // dim chunk: elems hl*8 .. hl*8+7
    const int rs = L >> 4;       // row-select within the 2-row read
    const int node = blockIdx.x * 8 + (t >> 5);
    if (node >= N) return;

    const int start = row_ptr[node];
    const int end   = row_ptr[node + 1];

    float an[8], ae[8];
    #pragma unroll
    for (int j = 0; j < 8; ++j) { an[j] = 0.f; ae[j] = 0.f; }

    int e = start;
    for (; e + 1 < end; e += 2) {
        // rows e, e+1 as one 512B contiguous block across the half-wave
        const sx8 ev = *(const sx8*)(ecsr + (size_t)e * D + L * 8);
        const int s = esrcc[e + rs];
        const sx8 nv = *(const sx8*)(nfb + (size_t)s * D + hl * 8);
        #pragma unroll
        for (int j = 0; j < 8; ++j) {
            ae[j] += bf2f(ev[j]);
            an[j] += bf2f(nv[j]);
        }
    }
    if (e < end && rs == 0) {
        const sx8 ev = *(const sx8*)(ecsr + (size_t)e * D + hl * 8);
        const int s = esrcc[e];
        const sx8 nv = *(const sx8*)(nfb + (size_t)s * D + hl * 8);
        #pragma unroll
        for (int j = 0; j < 8; ++j) {
            ae[j] += bf2f(ev[j]);
            an[j] += bf2f(nv[j]);
        }
    }
    // combine rs=0/1 partials (lane k <-> k+16 hold same dims)
    #pragma unroll
    for (int j = 0; j < 8; ++j) {
        an[j] += __shfl_xor(an[j], 16);
        ae[j] += __shfl_xor(ae[j], 16);
    }
    if (rs == 0) {
        const sx8 self = *(const sx8*)(nfb + (size_t)node * D + hl * 8);
        sx8 xv, ev2;
        #pragma unroll
        for (int j = 0; j < 8; ++j) {
            xv[j]  = f2bf(bf2f(self[j]) + an[j]);
            ev2[j] = f2bf(ae[j]);
        }
        *(sx8*)(xbuf  + (size_t)node * D + hl * 8) = xv;
        *(sx8*)(agg_e + (size_t)node * D + hl * 8) = ev2;
    }
}

// ======= k_h1: h1 = xbuf @ W1 + b1 (bf16 MFMA), + BN stats atomics =======
// NOTE: xbuf and h1 alias (reads complete before epilogue writes) — no restrict
__global__ __launch_bounds__(256) void k_h1(const short* xbuf,
                                            const short* __restrict__ Wt1,
                                            const float* __restrict__ b1,
                                            short* h1,
                                            float* __restrict__ stats, int N) {
    const int t = threadIdx.x;
    const int lane = t & 63;
    const int w = t >> 6;
    const int l15 = lane & 15;
    const int kg = lane >> 4;
    const int row0 = blockIdx.x * 64;

    bf16x8 bfr[4][2];
    #pragma unroll
    for (int kt = 0; kt < 4; ++kt)
        #pragma unroll
        for (int cf = 0; cf < 2; ++cf)
            bfr[kt][cf] = *(const bf16x8*)(Wt1 + (w * 32 + cf * 16 + l15) * D +
                                           kt * 32 + kg * 8);

    f32x4 acc[4][2];
    #pragma unroll
    for (int rt = 0; rt < 4; ++rt) { acc[rt][0] = (f32x4)0.f; acc[rt][1] = (f32x4)0.f; }

    #pragma unroll
    for (int rt = 0; rt < 4; ++rt) {
        const int row = row0 + rt * 16 + l15;
        bf16x8 a0 = (bf16x8)(short)0, a1 = a0, a2 = a0, a3 = a0;
        if (row < N) {
            const short* xp = xbuf + (size_t)row * D + kg * 8;
            a0 = *(const bf16x8*)(xp);
            a1 = *(const bf16x8*)(xp + 32);
            a2 = *(const bf16x8*)(xp + 64);
            a3 = *(const bf16x8*)(xp + 96);
        }
        acc[rt][0] = __builtin_amdgcn_mfma_f32_16x16x32_bf16(a0, bfr[0][0], acc[rt][0], 0, 0, 0);
        acc[rt][1] = __builtin_amdgcn_mfma_f32_16x16x32_bf16(a0, bfr[0][1], acc[rt][1], 0, 0, 0);
        acc[rt][0] = __builtin_amdgcn_mfma_f32_16x16x32_bf16(a1, bfr[1][0], acc[rt][0], 0, 0, 0);
        acc[rt][1] = __builtin_amdgcn_mfma_f32_16x16x32_bf16(a1, bfr[1][1], acc[rt][1], 0, 0, 0);
        acc[rt][0] = __builtin_amdgcn_mfma_f32_16x16x32_bf16(a2, bfr[2][0], acc[rt][0], 0, 0, 0);
        acc[rt][1] = __builtin_amdgcn_mfma_f32_16x16x32_bf16(a2, bfr[2][1], acc[rt][1], 0, 0, 0);
        acc[rt][0] = __builtin_amdgcn_mfma_f32_16x16x32_bf16(a3, bfr[3][0], acc[rt][0], 0, 0, 0);
        acc[rt][1] = __builtin_amdgcn_mfma_f32_16x16x32_bf16(a3, bfr[3][1], acc[rt][1], 0, 0, 0);
    }

    const float bias0 = b1[w * 32 + l15];
    const float bias1 = b1[w * 32 + 16 + l15];
    float cs0 = 0.f, cq0 = 0.f, cs1 = 0.f, cq1 = 0.f;
    #pragma unroll
    for (int rt = 0; rt < 4; ++rt) {
        #pragma unroll
        for (int j = 0; j < 4; ++j) {
            const int row = row0 + rt * 16 + kg * 4 + j;
            if (row < N) {
                const float h0 = acc[rt][0][j] + bias0;
                const float hv = acc[rt][1][j] + bias1;
                h1[(size_t)row * D + w * 32 + l15]      = f2bf(h0);
                h1[(size_t)row * D + w * 32 + 16 + l15] = f2bf(hv);
                cs0 += h0; cq0 += h0 * h0;
                cs1 += hv; cq1 += hv * hv;
            }
        }
    }
    #pragma unroll
    for (int m = 16; m < 64; m <<= 1) {
        cs0 += __shfl_xor(cs0, m); cq0 += __shfl_xor(cq0, m);
        cs1 += __shfl_xor(cs1, m); cq1 += __shfl_xor(cq1, m);
    }
    if (lane < 16) {
        atomicAdd(stats + w * 32 + lane,            cs0);
        atomicAdd(stats + w * 32 + 16 + lane,       cs1);
        atomicAdd(stats + 128 + w * 32 + lane,      cq0);
        atomicAdd(stats + 128 + w * 32 + 16 + lane, cq1);
    }
}

// ==== k_out: out = relu(bn(h1))@W2 + agg_e@We + b2 + deg*be (bf16 MFMA) ====
__global__ __launch_bounds__(256) void k_out(const short* __restrict__ h1,
                                             const short* __restrict__ agg_e,
                                             const short* __restrict__ Wt2,
                                             const short* __restrict__ Wte,
                                             const float* __restrict__ stats,
                                             const float* __restrict__ gamma,
                                             const float* __restrict__ beta,
                                             const float* __restrict__ b2,
                                             const float* __restrict__ be,
                                             const float* __restrict__ degf,
                                             float* __restrict__ out, int N) {
    __shared__ float scs[128], shs[128];
    const int t = threadIdx.x;
    if (t < 128) {
        const float invN = 1.0f / (float)N;
        const float mu = stats[t] * invN;
        const float var = stats[128 + t] * invN - mu * mu;
        const float sc = gamma[t] * rsqrtf(var + 1e-5f);
        scs[t] = sc;
        shs[t] = beta[t] - mu * sc;
    }
    __syncthreads();

    const int lane = t & 63;
    const int w = t >> 6;
    const int l15 = lane & 15;
    const int kg = lane >> 4;
    const int row0 = blockIdx.x * 64;

    f32x4 acc[4][2];
    #pragma unroll
    for (int rt = 0; rt < 4; ++rt) { acc[rt][0] = (f32x4)0.f; acc[rt][1] = (f32x4)0.f; }

    bf16x8 bfr[4][2];

    // ---- phase A: relu(bn(h1)) @ W2 ----
    #pragma unroll
    for (int kt = 0; kt < 4; ++kt)
        #pragma unroll
        for (int cf = 0; cf < 2; ++cf)
            bfr[kt][cf] = *(const bf16x8*)(Wt2 + (w * 32 + cf * 16 + l15) * D +
                                           kt * 32 + kg * 8);

    #pragma unroll
    for (int rt = 0; rt < 4; ++rt) {
        const int row = row0 + rt * 16 + l15;
        #pragma unroll
        for (int kt = 0; kt < 4; ++kt) {
            bf16x8 raw = (bf16x8)(short)0;
            if (row < N)
                raw = *(const bf16x8*)(h1 + (size_t)row * D + kt * 32 + kg * 8);
            const int k0 = kt * 32 + kg * 8;
            const float4 sa = *(const float4*)(scs + k0);
            const float4 sb = *(const float4*)(scs + k0 + 4);
            const float4 ha = *(const float4*)(shs + k0);
            const float4 hb = *(const float4*)(shs + k0 + 4);
            bf16x8 afr;
            afr[0] = f2bf(fmaxf(bf2f(raw[0]) * sa.x + ha.x, 0.f));
            afr[1] = f2bf(fmaxf(bf2f(raw[1]) * sa.y + ha.y, 0.f));
            afr[2] = f2bf(fmaxf(bf2f(raw[2]) * sa.z + ha.z, 0.f));
            afr[3] = f2bf(fmaxf(bf2f(raw[3]) * sa.w + ha.w, 0.f));
            afr[4] = f2bf(fmaxf(bf2f(raw[4]) * sb.x + hb.x, 0.f));
            afr[5] = f2bf(fmaxf(bf2f(raw[5]) * sb.y + hb.y, 0.f));
            afr[6] = f2bf(fmaxf(bf2f(raw[6]) * sb.z + hb.z, 0.f));
            afr[7] = f2bf(fmaxf(bf2f(raw[7]) * sb.w + hb.w, 0.f));
            acc[rt][0] = __builtin_amdgcn_mfma_f32_16x16x32_bf16(afr, bfr[kt][0], acc[rt][0], 0, 0, 0);
            acc[rt][1] = __builtin_amdgcn_mfma_f32_16x16x32_bf16(afr, bfr[kt][1], acc[rt][1], 0, 0, 0);
        }
    }

    // ---- phase B: agg_e @ We ----
    #pragma unroll
    for (int kt = 0; kt < 4; ++kt)
        #pragma unroll
        for (int cf = 0; cf < 2; ++cf)
            bfr[kt][cf] = *(const bf16x8*)(Wte + (w * 32 + cf * 16 + l15) * D +
                                           kt * 32 + kg * 8);

    #pragma unroll
    for (int rt = 0; rt < 4; ++rt) {
        const int row = row0 + rt * 16 + l15;
        bf16x8 a0 = (bf16x8)(short)0, a1 = a0, a2 = a0, a3 = a0;
        if (row < N) {
            const short* ap = agg_e + (size_t)row * D + kg * 8;
            a0 = *(const bf16x8*)(ap);
            a1 = *(const bf16x8*)(ap + 32);
            a2 = *(const bf16x8*)(ap + 64);
            a3 = *(const bf16x8*)(ap + 96);
        }
        acc[rt][0] = __builtin_amdgcn_mfma_f32_16x16x32_bf16(a0, bfr[0][0], acc[rt][0], 0, 0, 0);
        acc[rt][1] = __builtin_amdgcn_mfma_f32_16x16x32_bf16(a0, bfr[0][1], acc[rt][1], 0, 0, 0);
        acc[rt][0] = __builtin_amdgcn_mfma_f32_16x16x32_bf16(a1, bfr[1][0], acc[rt][0], 0, 0, 0);
        acc[rt][1] = __builtin_amdgcn_mfma_f32_16x16x32_bf16(a1, bfr[1][1], acc[rt][1], 0, 0, 0);
        acc[rt][0] = __builtin_amdgcn_mfma_f32_16x16x32_bf16(a2, bfr[2][0], acc[rt][0], 0, 0, 0);
        acc[rt][1] = __builtin_amdgcn_mfma_f32_16x16x32_bf16(a2, bfr[2][1], acc[rt][1], 0, 0, 0);
        acc[rt][0] = __builtin_amdgcn_mfma_f32_16x16x32_bf16(a3, bfr[3][0], acc[rt][0], 0, 0, 0);
        acc[rt][1] = __builtin_amdgcn_mfma_f32_16x16x32_bf16(a3, bfr[3][1], acc[rt][1], 0, 0, 0);
    }

    // ---- epilogue ----
    const float b2_0 = b2[w * 32 + l15];
    const float b2_1 = b2[w * 32 + 16 + l15];
    const float be_0 = be[w * 32 + l15];
    const float be_1 = be[w * 32 + 16 + l15];
    #pragma unroll
    for (int rt = 0; rt < 4; ++rt) {
        const int rbase = row0 + rt * 16 + kg * 4;
        float dgv[4];
        if (rbase + 3 < N) {
            *(float4*)dgv = *(const float4*)(degf + rbase);
        } else {
            #pragma unroll
            for (int j = 0; j < 4; ++j)
                dgv[j] = (rbase + j < N) ? degf[rbase + j] : 0.f;
        }
        #pragma unroll
        for (int j = 0; j < 4; ++j) {
            const int row = rbase + j;
            if (row < N) {
                out[(size_t)row * D + w * 32 + l15] =
                    acc[rt][0][j] + b2_0 + dgv[j] * be_0;
                out[(size_t)row * D + w * 32 + 16 + l15] =
                    acc[rt][1][j] + b2_1 + dgv[j] * be_1;
            }
        }
    }
}

extern "C" void kernel_launch(void* const* d_in, const int* in_sizes, int n_in,
                              void* d_out, int out_size, void* d_ws, size_t ws_size,
                              hipStream_t stream) {
    const float* nfeat = (const float*)d_in[0];
    const float* efeat = (const float*)d_in[1];
    const int*   src   = (const int*)d_in[2];
    const int*   dst   = (const int*)d_in[3];
    const float* W1    = (const float*)d_in[4];
    const float* b1    = (const float*)d_in[5];
    const float* gamma = (const float*)d_in[6];
    const float* beta  = (const float*)d_in[7];
    const float* W2    = (const float*)d_in[8];
    const float* b2    = (const float*)d_in[9];
    const float* We    = (const float*)d_in[10];
    const float* be    = (const float*)d_in[11];
    float* out = (float*)d_out;

    const int N = in_sizes[0] / D;
    const int E = in_sizes[2];
    const size_t ND = (size_t)N * D;

    // workspace layout — every segment a multiple of 16 B (h1 aliases xbuf)
    short* nfb    = (short*)d_ws;                // N*D bf16
    short* xbuf   = nfb + ND;                    // N*D bf16
    short* h1     = xbuf;                        // aliased
    short* agg_e  = xbuf + ND;                   // N*D bf16
    short* Wt1    = agg_e + ND;                  // 16384
    short* Wt2    = Wt1 + 16384;
    short* Wte    = Wt2 + 16384;
    float* stats  = (float*)(Wte + 16384);       // 256
    float* degf   = stats + 256;                 // N
    int*   row_ptr= (int*)(degf + N);            // N+16
    int*   cursor = row_ptr + (N + 16);          // N+16
    int*   cnt    = cursor + (N + 16);           // N+16
    int*   pos    = cnt + (N + 16);              // E
    int*   esrcc  = pos + E;                     // E
    short* ecsr   = (short*)(esrcc + E);         // E*D bf16 (~205 MB)

    const int nbConv = ((N * D) / 4 + 255) / 256;
    const int nbW    = 192;
    const int nbZ    = (N / 4 + 255) / 256;
    const int ebl4   = (E / 4 + 255) / 256;
    const int nb     = (N + 63) / 64;

    k_prep<<<nbConv + nbW + nbZ, 256, 0, stream>>>(nfeat, nfb, W1, W2, We,
                                                   Wt1, Wt2, Wte, cnt, stats,
                                                   N, nbConv, nbW);
    k_hist<<<ebl4, 256, 0, stream>>>(dst, cnt, E);
    k_scan<<<1, 1024, 0, stream>>>(cnt, row_ptr, cursor, degf, N);
    k_scatter<<<ebl4, 256, 0, stream>>>(src, dst, cursor, pos, esrcc, E);
    k_perm<<<(E + 15) / 16, 256, 0, stream>>>(efeat, pos, ecsr, E);
    k_sum<<<(N + 7) / 8, 256, 0, stream>>>(nfb, ecsr, row_ptr, esrcc,
                                           xbuf, agg_e, N);
    k_h1<<<nb, 256, 0, stream>>>(xbuf, Wt1, b1, h1, stats, N);
    k_out<<<nb, 256, 0, stream>>>(h1, agg_e, Wt2, Wte, stats, gamma, beta,
                                  b2, be, degf, out, N);
}

// Round 9
// 279.181 us; speedup vs baseline: 1.2633x; 1.2633x over previous
//
#include <hip/hip_runtime.h>

#define D 128

typedef __attribute__((ext_vector_type(8))) short bf16x8;   // 8 bf16 = 4 VGPR
typedef __attribute__((ext_vector_type(4))) float f32x4;    // MFMA C/D
typedef __attribute__((ext_vector_type(4))) float fx4;
typedef __attribute__((ext_vector_type(4))) short sx4;

static __device__ __forceinline__ short f2bf(float f) {  // RNE bf16 bits
    union { float f; unsigned u; } v; v.f = f;
    const unsigned r = v.u + 0x7FFFu + ((v.u >> 16) & 1u);
    return (short)(r >> 16);
}
static __device__ __forceinline__ float bf2f(short s) {
    union { unsigned u; float f; } v;
    v.u = ((unsigned)(unsigned short)s) << 16;
    return v.f;
}

// ===== k_prep: nfeat->bf16 convert + zero cnt/stats =====
__global__ __launch_bounds__(256) void k_prep(
    const float* __restrict__ nfeat, short* __restrict__ nfb,
    int* __restrict__ cnt, float* __restrict__ stats,
    int N, int nbConv)
{
    const int b = blockIdx.x, t = threadIdx.x;
    if (b < nbConv) {
        const int i = b * 256 + t;
        if (i < (N * D) / 4) {
            const float4 v = ((const float4*)nfeat)[i];
            short4 s;
            s.x = f2bf(v.x); s.y = f2bf(v.y); s.z = f2bf(v.z); s.w = f2bf(v.w);
            ((short4*)nfb)[i] = s;
        }
    } else {
        const int i = (b - nbConv) * 256 + t;
        if (i * 4 < N) ((int4*)cnt)[i] = make_int4(0, 0, 0, 0);
        if (b == nbConv && t < 256) stats[t] = 0.f;
    }
}

// ===== k_hist: histogram of dst (+ W transpose blocks appended) =====
__global__ void k_hist(const int* __restrict__ dst, int* __restrict__ cnt,
                       const float* __restrict__ W1, const float* __restrict__ W2,
                       const float* __restrict__ We, short* __restrict__ Wt1,
                       short* __restrict__ Wt2, short* __restrict__ Wte,
                       int E, int ebl) {
    if (blockIdx.x < (unsigned)ebl) {
        const int base = (blockIdx.x * 256 + threadIdx.x) * 4;
        if (base + 3 < E) {
            const int4 d4 = *(const int4*)(dst + base);
            atomicAdd(&cnt[d4.x], 1);
            atomicAdd(&cnt[d4.y], 1);
            atomicAdd(&cnt[d4.z], 1);
            atomicAdd(&cnt[d4.w], 1);
        } else {
            for (int e = base; e < E; ++e) atomicAdd(&cnt[dst[e]], 1);
        }
    } else {
        const int i = (blockIdx.x - ebl) * 256 + threadIdx.x;  // 0 .. 49151
        const int m = i >> 14;
        const int idx = i & 16383;
        const int k = idx >> 7, n = idx & 127;
        const float* W = (m == 0) ? W1 : (m == 1) ? W2 : We;
        short* Wt = (m == 0) ? Wt1 : (m == 1) ? Wt2 : Wte;
        Wt[n * 128 + k] = f2bf(W[k * 128 + n]);
    }
}

// ===== single-block multi-tile exclusive scan =====
__global__ __launch_bounds__(1024) void k_scan(
    const int* __restrict__ cnt, int* __restrict__ row_ptr,
    int* __restrict__ cursor, float* __restrict__ degf, int N)
{
    __shared__ int ws[17];
    const int t = threadIdx.x, lane = t & 63, wid = t >> 6;
    int carry = 0;
    const int ntiles = (N + 4095) / 4096;
    for (int tile = 0; tile < ntiles; ++tile) {
        const int base = tile * 4096 + t * 4;
        int4 v = make_int4(0, 0, 0, 0);
        if (base + 3 < N) v = *(const int4*)(cnt + base);
        else {
            if (base     < N) v.x = cnt[base];
            if (base + 1 < N) v.y = cnt[base + 1];
            if (base + 2 < N) v.z = cnt[base + 2];
            if (base + 3 < N) v.w = cnt[base + 3];
        }
        const int s = v.x + v.y + v.z + v.w;
        int incl = s;
        #pragma unroll
        for (int off = 1; off < 64; off <<= 1) {
            const int u = __shfl_up(incl, off);
            if (lane >= off) incl += u;
        }
        if (lane == 63) ws[wid] = incl;
        __syncthreads();
        if (t < 16) {
            const int wv = ws[t];
            int wincl = wv;
            #pragma unroll
            for (int off = 1; off < 16; off <<= 1) {
                const int u = __shfl_up(wincl, off);
                if (t >= off) wincl += u;
            }
            ws[t] = wincl - wv;
            if (t == 15) ws[16] = wincl;
        }
        __syncthreads();
        const int ex = carry + ws[wid] + (incl - s);
        if (base + 3 < N) {
            const int4 rp = make_int4(ex, ex + v.x, ex + v.x + v.y,
                                      ex + v.x + v.y + v.z);
            *(int4*)(row_ptr + base) = rp;
            *(int4*)(cursor + base)  = rp;
            *(float4*)(degf + base)  =
                make_float4((float)v.x, (float)v.y, (float)v.z, (float)v.w);
        } else {
            int run = ex;
            if (base < N)     { row_ptr[base]   = run; cursor[base]   = run; degf[base]   = (float)v.x; run += v.x; }
            if (base + 1 < N) { row_ptr[base+1] = run; cursor[base+1] = run; degf[base+1] = (float)v.y; run += v.y; }
            if (base + 2 < N) { row_ptr[base+2] = run; cursor[base+2] = run; degf[base+2] = (float)v.z; run += v.z; }
            if (base + 3 < N) { row_ptr[base+3] = run; cursor[base+3] = run; degf[base+3] = (float)v.w; }
        }
        carry += ws[16];
        __syncthreads();
    }
    if (t == 0) row_ptr[N] = carry;
}

__global__ void k_scatter(const int* __restrict__ src, const int* __restrict__ dst,
                          int* __restrict__ cursor,
                          int2* __restrict__ epair, int E) {
    const int base = (blockIdx.x * 256 + threadIdx.x) * 4;
    if (base + 3 < E) {
        const int4 d4 = *(const int4*)(dst + base);
        const int4 s4 = *(const int4*)(src + base);
        int p;
        p = atomicAdd(&cursor[d4.x], 1); epair[p] = make_int2(base + 0, s4.x);
        p = atomicAdd(&cursor[d4.y], 1); epair[p] = make_int2(base + 1, s4.y);
        p = atomicAdd(&cursor[d4.z], 1); epair[p] = make_int2(base + 2, s4.z);
        p = atomicAdd(&cursor[d4.w], 1); epair[p] = make_int2(base + 3, s4.w);
    } else {
        for (int e = base; e < E; ++e) {
            const int p = atomicAdd(&cursor[dst[e]], 1);
            epair[p] = make_int2(e, src[e]);
        }
    }
}

// ===== gather: HALF-WAVE per node (8 nodes/block), 8-deep edge pipeline =====
// xbuf = bf16(nfb[node] + sum nfb[src]); agg_e = bf16(sum efeat[e])
__global__ __launch_bounds__(256) void k_gather(
    const short* __restrict__ nfb, const float* __restrict__ efeat,
    const int* __restrict__ row_ptr, const int2* __restrict__ epair,
    short* __restrict__ xbuf, short* __restrict__ agg_e, int N)
{
    const int t = threadIdx.x;
    const int c = t & 31;                  // float4/short4 chunk of the row
    const int node = blockIdx.x * 8 + (t >> 5);
    if (node >= N) return;

    const int start = row_ptr[node];
    const int end   = row_ptr[node + 1];

    fx4 an = {0.f, 0.f, 0.f, 0.f};
    fx4 ae = {0.f, 0.f, 0.f, 0.f};
    int e = start;
    for (; e + 7 < end; e += 8) {          // 8 edges in flight per half-wave
        fx4 ev[8]; sx4 nv[8];
        #pragma unroll
        for (int u = 0; u < 8; ++u) {
            const int2 p = epair[e + u];
            ev[u] = __builtin_nontemporal_load((const fx4*)(efeat + (size_t)p.x * D) + c);
            nv[u] = *((const sx4*)(nfb + (size_t)p.y * D) + c);
        }
        #pragma unroll
        for (int u = 0; u < 8; ++u)
            #pragma unroll
            for (int j = 0; j < 4; ++j) {
                ae[j] += ev[u][j];
                an[j] += bf2f(nv[u][j]);
            }
    }
    for (; e + 1 < end; e += 2) {
        const int2 p0 = epair[e];
        const int2 p1 = epair[e + 1];
        const fx4 ev0 = __builtin_nontemporal_load((const fx4*)(efeat + (size_t)p0.x * D) + c);
        const fx4 ev1 = __builtin_nontemporal_load((const fx4*)(efeat + (size_t)p1.x * D) + c);
        const sx4 nv0 = *((const sx4*)(nfb + (size_t)p0.y * D) + c);
        const sx4 nv1 = *((const sx4*)(nfb + (size_t)p1.y * D) + c);
        #pragma unroll
        for (int j = 0; j < 4; ++j) {
            ae[j] += ev0[j] + ev1[j];
            an[j] += bf2f(nv0[j]) + bf2f(nv1[j]);
        }
    }
    if (e < end) {
        const int2 p0 = epair[e];
        const fx4 ev0 = __builtin_nontemporal_load((const fx4*)(efeat + (size_t)p0.x * D) + c);
        const sx4 nv0 = *((const sx4*)(nfb + (size_t)p0.y * D) + c);
        #pragma unroll
        for (int j = 0; j < 4; ++j) {
            ae[j] += ev0[j];
            an[j] += bf2f(nv0[j]);
        }
    }

    const sx4 self = *((const sx4*)(nfb + (size_t)node * D) + c);
    sx4 xv, ev2;
    #pragma unroll
    for (int j = 0; j < 4; ++j) {
        xv[j]  = f2bf(bf2f(self[j]) + an[j]);
        ev2[j] = f2bf(ae[j]);
    }
    __builtin_nontemporal_store(xv,  (sx4*)(xbuf  + (size_t)node * D) + c);
    __builtin_nontemporal_store(ev2, (sx4*)(agg_e + (size_t)node * D) + c);
}

// ======= k_h1: h1 = xbuf @ W1 + b1 (bf16 MFMA), + BN stats atomics =======
// NOTE: xbuf and h1 alias (reads complete before epilogue writes) — no restrict
__global__ __launch_bounds__(256) void k_h1(const short* xbuf,
                                            const short* __restrict__ Wt1,
                                            const float* __restrict__ b1,
                                            short* h1,
                                            float* __restrict__ stats, int N) {
    const int t = threadIdx.x;
    const int lane = t & 63;
    const int w = t >> 6;
    const int l15 = lane & 15;
    const int kg = lane >> 4;
    const int row0 = blockIdx.x * 64;

    bf16x8 bfr[4][2];
    #pragma unroll
    for (int kt = 0; kt < 4; ++kt)
        #pragma unroll
        for (int cf = 0; cf < 2; ++cf)
            bfr[kt][cf] = *(const bf16x8*)(Wt1 + (w * 32 + cf * 16 + l15) * D +
                                           kt * 32 + kg * 8);

    f32x4 acc[4][2];
    #pragma unroll
    for (int rt = 0; rt < 4; ++rt) { acc[rt][0] = (f32x4)0.f; acc[rt][1] = (f32x4)0.f; }

    #pragma unroll
    for (int rt = 0; rt < 4; ++rt) {
        const int row = row0 + rt * 16 + l15;
        bf16x8 a0 = (bf16x8)(short)0, a1 = a0, a2 = a0, a3 = a0;
        if (row < N) {
            const short* xp = xbuf + (size_t)row * D + kg * 8;
            a0 = *(const bf16x8*)(xp);
            a1 = *(const bf16x8*)(xp + 32);
            a2 = *(const bf16x8*)(xp + 64);
            a3 = *(const bf16x8*)(xp + 96);
        }
        acc[rt][0] = __builtin_amdgcn_mfma_f32_16x16x32_bf16(a0, bfr[0][0], acc[rt][0], 0, 0, 0);
        acc[rt][1] = __builtin_amdgcn_mfma_f32_16x16x32_bf16(a0, bfr[0][1], acc[rt][1], 0, 0, 0);
        acc[rt][0] = __builtin_amdgcn_mfma_f32_16x16x32_bf16(a1, bfr[1][0], acc[rt][0], 0, 0, 0);
        acc[rt][1] = __builtin_amdgcn_mfma_f32_16x16x32_bf16(a1, bfr[1][1], acc[rt][1], 0, 0, 0);
        acc[rt][0] = __builtin_amdgcn_mfma_f32_16x16x32_bf16(a2, bfr[2][0], acc[rt][0], 0, 0, 0);
        acc[rt][1] = __builtin_amdgcn_mfma_f32_16x16x32_bf16(a2, bfr[2][1], acc[rt][1], 0, 0, 0);
        acc[rt][0] = __builtin_amdgcn_mfma_f32_16x16x32_bf16(a3, bfr[3][0], acc[rt][0], 0, 0, 0);
        acc[rt][1] = __builtin_amdgcn_mfma_f32_16x16x32_bf16(a3, bfr[3][1], acc[rt][1], 0, 0, 0);
    }

    const float bias0 = b1[w * 32 + l15];
    const float bias1 = b1[w * 32 + 16 + l15];
    float cs0 = 0.f, cq0 = 0.f, cs1 = 0.f, cq1 = 0.f;
    #pragma unroll
    for (int rt = 0; rt < 4; ++rt) {
        #pragma unroll
        for (int j = 0; j < 4; ++j) {
            const int row = row0 + rt * 16 + kg * 4 + j;
            if (row < N) {
                const float h0 = acc[rt][0][j] + bias0;
                const float hv = acc[rt][1][j] + bias1;
                h1[(size_t)row * D + w * 32 + l15]      = f2bf(h0);
                h1[(size_t)row * D + w * 32 + 16 + l15] = f2bf(hv);
                cs0 += h0; cq0 += h0 * h0;
                cs1 += hv; cq1 += hv * hv;
            }
        }
    }
    #pragma unroll
    for (int m = 16; m < 64; m <<= 1) {
        cs0 += __shfl_xor(cs0, m); cq0 += __shfl_xor(cq0, m);
        cs1 += __shfl_xor(cs1, m); cq1 += __shfl_xor(cq1, m);
    }
    if (lane < 16) {
        atomicAdd(stats + w * 32 + lane,            cs0);
        atomicAdd(stats + w * 32 + 16 + lane,       cs1);
        atomicAdd(stats + 128 + w * 32 + lane,      cq0);
        atomicAdd(stats + 128 + w * 32 + 16 + lane, cq1);
    }
}

// ==== k_out: out = relu(bn(h1))@W2 + agg_e@We + b2 + deg*be (bf16 MFMA) ====
__global__ __launch_bounds__(256) void k_out(const short* __restrict__ h1,
                                             const short* __restrict__ agg_e,
                                             const short* __restrict__ Wt2,
                                             const short* __restrict__ Wte,
                                             const float* __restrict__ stats,
                                             const float* __restrict__ gamma,
                                             const float* __restrict__ beta,
                                             const float* __restrict__ b2,
                                             const float* __restrict__ be,
                                             const float* __restrict__ degf,
                                             float* __restrict__ out, int N) {
    __shared__ float scs[128], shs[128];
    const int t = threadIdx.x;
    if (t < 128) {
        const float invN = 1.0f / (float)N;
        const float mu = stats[t] * invN;
        const float var = stats[128 + t] * invN - mu * mu;
        const float sc = gamma[t] * rsqrtf(var + 1e-5f);
        scs[t] = sc;
        shs[t] = beta[t] - mu * sc;
    }
    __syncthreads();

    const int lane = t & 63;
    const int w = t >> 6;
    const int l15 = lane & 15;
    const int kg = lane >> 4;
    const int row0 = blockIdx.x * 64;

    f32x4 acc[4][2];
    #pragma unroll
    for (int rt = 0; rt < 4; ++rt) { acc[rt][0] = (f32x4)0.f; acc[rt][1] = (f32x4)0.f; }

    bf16x8 bfr[4][2];

    // ---- phase A: relu(bn(h1)) @ W2 ----
    #pragma unroll
    for (int kt = 0; kt < 4; ++kt)
        #pragma unroll
        for (int cf = 0; cf < 2; ++cf)
            bfr[kt][cf] = *(const bf16x8*)(Wt2 + (w * 32 + cf * 16 + l15) * D +
                                           kt * 32 + kg * 8);

    #pragma unroll
    for (int rt = 0; rt < 4; ++rt) {
        const int row = row0 + rt * 16 + l15;
        #pragma unroll
        for (int kt = 0; kt < 4; ++kt) {
            bf16x8 raw = (bf16x8)(short)0;
            if (row < N)
                raw = *(const bf16x8*)(h1 + (size_t)row * D + kt * 32 + kg * 8);
            const int k0 = kt * 32 + kg * 8;
            const float4 sa = *(const float4*)(scs + k0);
            const float4 sb = *(const float4*)(scs + k0 + 4);
            const float4 ha = *(const float4*)(shs + k0);
            const float4 hb = *(const float4*)(shs + k0 + 4);
            bf16x8 afr;
            afr[0] = f2bf(fmaxf(bf2f(raw[0]) * sa.x + ha.x, 0.f));
            afr[1] = f2bf(fmaxf(bf2f(raw[1]) * sa.y + ha.y, 0.f));
            afr[2] = f2bf(fmaxf(bf2f(raw[2]) * sa.z + ha.z, 0.f));
            afr[3] = f2bf(fmaxf(bf2f(raw[3]) * sa.w + ha.w, 0.f));
            afr[4] = f2bf(fmaxf(bf2f(raw[4]) * sb.x + hb.x, 0.f));
            afr[5] = f2bf(fmaxf(bf2f(raw[5]) * sb.y + hb.y, 0.f));
            afr[6] = f2bf(fmaxf(bf2f(raw[6]) * sb.z + hb.z, 0.f));
            afr[7] = f2bf(fmaxf(bf2f(raw[7]) * sb.w + hb.w, 0.f));
            acc[rt][0] = __builtin_amdgcn_mfma_f32_16x16x32_bf16(afr, bfr[kt][0], acc[rt][0], 0, 0, 0);
            acc[rt][1] = __builtin_amdgcn_mfma_f32_16x16x32_bf16(afr, bfr[kt][1], acc[rt][1], 0, 0, 0);
        }
    }

    // ---- phase B: agg_e @ We ----
    #pragma unroll
    for (int kt = 0; kt < 4; ++kt)
        #pragma unroll
        for (int cf = 0; cf < 2; ++cf)
            bfr[kt][cf] = *(const bf16x8*)(Wte + (w * 32 + cf * 16 + l15) * D +
                                           kt * 32 + kg * 8);

    #pragma unroll
    for (int rt = 0; rt < 4; ++rt) {
        const int row = row0 + rt * 16 + l15;
        bf16x8 a0 = (bf16x8)(short)0, a1 = a0, a2 = a0, a3 = a0;
        if (row < N) {
            const short* ap = agg_e + (size_t)row * D + kg * 8;
            a0 = *(const bf16x8*)(ap);
            a1 = *(const bf16x8*)(ap + 32);
            a2 = *(const bf16x8*)(ap + 64);
            a3 = *(const bf16x8*)(ap + 96);
        }
        acc[rt][0] = __builtin_amdgcn_mfma_f32_16x16x32_bf16(a0, bfr[0][0], acc[rt][0], 0, 0, 0);
        acc[rt][1] = __builtin_amdgcn_mfma_f32_16x16x32_bf16(a0, bfr[0][1], acc[rt][1], 0, 0, 0);
        acc[rt][0] = __builtin_amdgcn_mfma_f32_16x16x32_bf16(a1, bfr[1][0], acc[rt][0], 0, 0, 0);
        acc[rt][1] = __builtin_amdgcn_mfma_f32_16x16x32_bf16(a1, bfr[1][1], acc[rt][1], 0, 0, 0);
        acc[rt][0] = __builtin_amdgcn_mfma_f32_16x16x32_bf16(a2, bfr[2][0], acc[rt][0], 0, 0, 0);
        acc[rt][1] = __builtin_amdgcn_mfma_f32_16x16x32_bf16(a2, bfr[2][1], acc[rt][1], 0, 0, 0);
        acc[rt][0] = __builtin_amdgcn_mfma_f32_16x16x32_bf16(a3, bfr[3][0], acc[rt][0], 0, 0, 0);
        acc[rt][1] = __builtin_amdgcn_mfma_f32_16x16x32_bf16(a3, bfr[3][1], acc[rt][1], 0, 0, 0);
    }

    // ---- epilogue ----
    const float b2_0 = b2[w * 32 + l15];
    const float b2_1 = b2[w * 32 + 16 + l15];
    const float be_0 = be[w * 32 + l15];
    const float be_1 = be[w * 32 + 16 + l15];
    #pragma unroll
    for (int rt = 0; rt < 4; ++rt) {
        const int rbase = row0 + rt * 16 + kg * 4;
        float dgv[4];
        if (rbase + 3 < N) {
            *(float4*)dgv = *(const float4*)(degf + rbase);
        } else {
            #pragma unroll
            for (int j = 0; j < 4; ++j)
                dgv[j] = (rbase + j < N) ? degf[rbase + j] : 0.f;
        }
        #pragma unroll
        for (int j = 0; j < 4; ++j) {
            const int row = rbase + j;
            if (row < N) {
                out[(size_t)row * D + w * 32 + l15] =
                    acc[rt][0][j] + b2_0 + dgv[j] * be_0;
                out[(size_t)row * D + w * 32 + 16 + l15] =
                    acc[rt][1][j] + b2_1 + dgv[j] * be_1;
            }
        }
    }
}

extern "C" void kernel_launch(void* const* d_in, const int* in_sizes, int n_in,
                              void* d_out, int out_size, void* d_ws, size_t ws_size,
                              hipStream_t stream) {
    const float* nfeat = (const float*)d_in[0];
    const float* efeat = (const float*)d_in[1];
    const int*   src   = (const int*)d_in[2];
    const int*   dst   = (const int*)d_in[3];
    const float* W1    = (const float*)d_in[4];
    const float* b1    = (const float*)d_in[5];
    const float* gamma = (const float*)d_in[6];
    const float* beta  = (const float*)d_in[7];
    const float* W2    = (const float*)d_in[8];
    const float* b2    = (const float*)d_in[9];
    const float* We    = (const float*)d_in[10];
    const float* be    = (const float*)d_in[11];
    float* out = (float*)d_out;

    const int N = in_sizes[0] / D;
    const int E = in_sizes[2];
    const size_t ND = (size_t)N * D;

    // workspace layout — every segment a multiple of 16 B (h1 aliases xbuf)
    short* nfb    = (short*)d_ws;                // N*D bf16
    short* xbuf   = nfb + ND;                    // N*D bf16
    short* h1     = xbuf;                        // aliased
    short* agg_e  = xbuf + ND;                   // N*D bf16
    short* Wt1    = agg_e + ND;                  // 16384
    short* Wt2    = Wt1 + 16384;
    short* Wte    = Wt2 + 16384;
    float* stats  = (float*)(Wte + 16384);       // 256
    float* degf   = stats + 256;                 // N
    int*   row_ptr= (int*)(degf + N);            // N+16
    int*   cursor = row_ptr + (N + 16);          // N+16
    int*   cnt    = cursor + (N + 16);           // N+16
    int2*  epair  = (int2*)(cnt + (N + 16));     // E

    const int nbConv = ((N * D) / 4 + 255) / 256;
    const int nbZ    = (N / 4 + 255) / 256;
    const int ebl4   = (E / 4 + 255) / 256;
    const int nb     = (N + 63) / 64;

    k_prep<<<nbConv + nbZ, 256, 0, stream>>>(nfeat, nfb, cnt, stats, N, nbConv);
    k_hist<<<ebl4 + 192, 256, 0, stream>>>(dst, cnt, W1, W2, We,
                                           Wt1, Wt2, Wte, E, ebl4);
    k_scan<<<1, 1024, 0, stream>>>(cnt, row_ptr, cursor, degf, N);
    k_scatter<<<ebl4, 256, 0, stream>>>(src, dst, cursor, epair, E);
    k_gather<<<(N + 7) / 8, 256, 0, stream>>>(nfb, efeat, row_ptr, epair,
                                              xbuf, agg_e, N);
    k_h1<<<nb, 256, 0, stream>>>(xbuf, Wt1, b1, h1, stats, N);
    k_out<<<nb, 256, 0, stream>>>(h1, agg_e, Wt2, Wte, stats, gamma, beta,
                                  b2, be, degf, out, N);
}